// Round 1
// baseline (70.787 us; speedup 1.0000x reference)
//
#include <hip/hip_runtime.h>

namespace {

constexpr int kB      = 8;
constexpr int kT      = 4096;
constexpr int kC4     = 256;   // 1024 f32 channels viewed as float4
constexpr int kNSeg   = 64;
constexpr int kSegLen = 64;    // kT / kNSeg

// K1: partial[b][seg][c4] = sum over the segment's 64 timesteps (float4-wide).
__global__ __launch_bounds__(256) void seg_sum_kernel(const float4* __restrict__ x,
                                                      float4* __restrict__ part) {
    const int tid = blockIdx.x * 256 + threadIdx.x;        // [0, kB*kNSeg*kC4)
    const int c4  = tid & (kC4 - 1);                       // varies per lane -> coalesced
    const int seg = (tid >> 8) & (kNSeg - 1);              // uniform per block
    const int b   = tid >> 14;

    const float4* p = x + ((size_t)(b * kT + seg * kSegLen)) * kC4 + c4;
    float sx = 0.f, sy = 0.f, sz = 0.f, sw = 0.f;
#pragma unroll 8
    for (int i = 0; i < kSegLen; ++i) {
        const float4 v = p[(size_t)i * kC4];
        sx += v.x; sy += v.y; sz += v.z; sw += v.w;
    }
    part[tid] = make_float4(sx, sy, sz, sw);               // layout matches tid order
}

// K2: offset = sum of partials of earlier segments, then rescan segment and
// write (offset + running) / (t+1).
__global__ __launch_bounds__(256) void scan_write_kernel(const float4* __restrict__ x,
                                                         const float4* __restrict__ part,
                                                         float4* __restrict__ out) {
    const int tid = blockIdx.x * 256 + threadIdx.x;
    const int c4  = tid & (kC4 - 1);
    const int seg = (tid >> 8) & (kNSeg - 1);              // uniform per block
    const int b   = tid >> 14;

    float ox = 0.f, oy = 0.f, oz = 0.f, ow = 0.f;
    const float4* pp = part + (size_t)b * kNSeg * kC4 + c4;
    for (int s = 0; s < seg; ++s) {                        // uniform trip count
        const float4 v = pp[(size_t)s * kC4];
        ox += v.x; oy += v.y; oz += v.z; ow += v.w;
    }

    const size_t base = ((size_t)(b * kT + seg * kSegLen)) * kC4 + c4;
    const float4* p = x + base;
    float4* o       = out + base;
    const int t0    = seg * kSegLen;
#pragma unroll 4
    for (int i = 0; i < kSegLen; ++i) {
        const float4 v = p[(size_t)i * kC4];
        ox += v.x; oy += v.y; oz += v.z; ow += v.w;
        const float inv = 1.0f / (float)(t0 + i + 1);
        o[(size_t)i * kC4] = make_float4(ox * inv, oy * inv, oz * inv, ow * inv);
    }
}

}  // namespace

extern "C" void kernel_launch(void* const* d_in, const int* in_sizes, int n_in,
                              void* d_out, int out_size, void* d_ws, size_t ws_size,
                              hipStream_t stream) {
    const float4* x   = (const float4*)d_in[0];
    float4* out       = (float4*)d_out;
    float4* part      = (float4*)d_ws;       // kB*kNSeg*kC4 * 16 B = 2 MiB scratch
    constexpr int total = kB * kNSeg * kC4;  // 131072 threads per kernel
    seg_sum_kernel<<<total / 256, 256, 0, stream>>>(x, part);
    scan_write_kernel<<<total / 256, 256, 0, stream>>>(x, part, out);
}